// Round 18
// baseline (370.220 us; speedup 1.0000x reference)
//
#include <hip/hip_runtime.h>
#include <hip/hip_bf16.h>

typedef __attribute__((ext_vector_type(8))) short  short8;
typedef __attribute__((ext_vector_type(4))) float  f32x4;

#define HIDDEN   256
#define NLAYERS  4
#define PPW      32                    // 2 pipelined blocks x 16 points
#define NPTS     131072
#define NWG      (NPTS / PPW)          // 4096
#define NSTATE   4                     // h, g0, g1, c = gt - (s0+s1)
#define PLANE    32768                 // bytes per block plane

// workspace layout (bytes)
#define WS_PARTIALS   0                          // 4096 doubles = 32 KB
#define WS_WHI        65536                      // 512 KB bf16 W fragments

__device__ __forceinline__ unsigned short f2bf(float f) {
    return __builtin_bit_cast(unsigned short, __float2bfloat16(f));
}
__device__ __forceinline__ float bf2f(unsigned short h) {
    return __uint_as_float(((unsigned)h) << 16);
}
__device__ __forceinline__ unsigned pack2(float a, float b) {
    __hip_bfloat162 h2 = __float22bfloat162_rn(make_float2(a, b));
    unsigned u;
    __builtin_memcpy(&u, &h2, sizeof(u));
    return u;
}
__device__ __forceinline__ float fast_tanh(float z) {
    float e = __expf(2.f * z);
    return 1.f - __fdividef(2.f, e + 1.f);
}

// ---------------- weight prep: W_h -> bf16, 16x16x32-A fragments ----------------
// Fragment (layer, jt, kt): lane l holds W[k][j] for j = jt*16 + (l&15),
// k = kt*32 + (l>>4)*8 + e (e=0..7).
__global__ void prep_w(const float* __restrict__ Wh, unsigned short* __restrict__ whi)
{
    int b    = blockIdx.x;               // 512 = 4 layers x 16 jt x 8 kt
    int lay  = b >> 7;
    int jt   = (b >> 3) & 15;
    int kt   = b & 7;
    int lane = threadIdx.x;              // 64
    int j    = jt * 16 + (lane & 15);
    int k0   = kt * 32 + (lane >> 4) * 8;
    const float* W = Wh + lay * 65536;
    int base = ((lay * 16 + jt) * 8 + kt) * 512 + lane * 8;
#pragma unroll
    for (int e = 0; e < 8; ++e)
        whi[base + e] = f2bf(W[(k0 + e) * HIDDEN + j]);
}

// half-GEMM (4 k-tiles) into ACC from plane PBASE with W fragment base WB
#define GEMM_QTR(ACC, PBASE, WB, KT0)                                                    \
    _Pragma("unroll")                                                                    \
    for (int kt = (KT0); kt < (KT0) + 4; ++kt) {                                         \
        short8 wh0 = *(const short8*)((WB) + 0 * 4096 + kt * 512);                       \
        short8 wh1 = *(const short8*)((WB) + 1 * 4096 + kt * 512);                       \
        short8 s_[NSTATE];                                                               \
        _Pragma("unroll")                                                                \
        for (int mt = 0; mt < NSTATE; ++mt)                                              \
            s_[mt] = *(const short8*)((PBASE) + lane * 16 + (mt * 8 + kt) * 1024);       \
        __builtin_amdgcn_s_setprio(1);                                                   \
        _Pragma("unroll")                                                                \
        for (int mt = 0; mt < NSTATE; ++mt) {                                            \
            ACC[0][mt] = __builtin_amdgcn_mfma_f32_16x16x32_bf16(wh0, s_[mt], ACC[0][mt], 0, 0, 0); \
            ACC[1][mt] = __builtin_amdgcn_mfma_f32_16x16x32_bf16(wh1, s_[mt], ACC[1][mt], 0, 0, 0); \
        }                                                                                \
        __builtin_amdgcn_s_setprio(0);                                                   \
    }

// tanh-jet for one jj (16 j x 4 rows per lane quad), writes plane POUT
#define TANH_UNIT(ACC, POUT, JJ, BIAS, SLO)                                              \
    {                                                                                    \
        const int j0 = (swid * 2 + (JJ)) * 16 + q * 4;                                   \
        const int kt = j0 >> 5, kg = (j0 >> 3) & 3, e0 = j0 & 7;                         \
        const int sub = (kg * 16 + p_) * 16 + e0 * 2;                                    \
        float o[NSTATE][4];                                                              \
        _Pragma("unroll")                                                                \
        for (int r = 0; r < 4; ++r) {                                                    \
            float z0 = ACC[JJ][0][r] + (BIAS)[r];                                        \
            float z1 = ACC[JJ][1][r], z2 = ACC[JJ][2][r], zc = ACC[JJ][3][r];            \
            float a  = fast_tanh(z0);                                                    \
            float td = 1.f - a * a;                                                      \
            float t2 = 2.f * a * td;                                                     \
            o[0][r] = a; o[1][r] = td * z1; o[2][r] = td * z2;                           \
            o[3][r] = fmaf(td, zc, t2 * fmaf(z1, z1, z2 * z2));                          \
        }                                                                                \
        _Pragma("unroll")                                                                \
        for (int s = 0; s < NSTATE; ++s) {                                               \
            if (s < (SLO)) continue;                                                     \
            uint2 wv = { pack2(o[s][0], o[s][1]), pack2(o[s][2], o[s][3]) };             \
            *(uint2*)((POUT) + (s * 8 + kt) * 1024 + sub) = wv;                          \
        }                                                                                \
    }

#define ACC_ZERO(ACC)                                                                    \
    _Pragma("unroll")                                                                    \
    for (int jj = 0; jj < 2; ++jj)                                                       \
        _Pragma("unroll")                                                                \
        for (int mt = 0; mt < NSTATE; ++mt)                                              \
            ACC[jj][mt] = (f32x4){0.f, 0.f, 0.f, 0.f};

// ---------------- fused PINN kernel: 512 thr (8 waves), 64 KB LDS, 1 WG/CU ----------------
// Two independent 16-point blocks A/B per WG, software-pipelined so every phase
// contains both MFMA (GEMM of one block) and VALU (tanh of the other block):
//   prologue: accA = GEMM_A(0)
//   layer l:  phase X: GEMM_B(l) || tanh_A(l)   (B-plane reads, A-plane writes: disjoint)
//             phase Y: GEMM_A(l+1) || tanh_B(l) (A-plane reads, B-plane writes: disjoint)
// launch_bounds(512,2): 256-reg budget so accA+accB (64) + operands never spill
// (R17's (512,4)=128-reg budget spilled: WRITE_SIZE 221 MB). In-stream MFMA||VALU
// interleave replaces cross-WG stagger, so 1 WG/CU (2 waves/SIMD) suffices.
__global__ __launch_bounds__(512, 2)
void pinn_mfma(const float* __restrict__ X,
               const float* __restrict__ W_in, const float* __restrict__ b_in,
               const float* __restrict__ b_h,  const float* __restrict__ W_out,
               const unsigned short* __restrict__ whi,
               double* __restrict__ partials)
{
    extern __shared__ char lds[];
    char*   PA  = lds;                        // block A plane
    char*   PB  = lds + PLANE;                // block B plane
    float*  red = (float*)lds;                // 1024 floats, aliases PA s=0 kt0..3 (dead)
    double* sq  = (double*)(lds + 4096);      // 32 doubles, aliases PA s=0 kt4

    const int tid  = threadIdx.x;
    const int lane = tid & 63;
    const int swid = __builtin_amdgcn_readfirstlane(tid >> 6);   // wave id, SGPR
    const int q    = lane >> 4;
    const int p_   = lane & 15;
    const int wg   = blockIdx.x;
    const int pt0  = wg * PPW;

    // ---- input layer: both blocks; thread (p = tid&15, jq0 = tid>>4) ----
    {
        const int p   = tid & 15;
        const int jq0 = tid >> 4;                // 0..31
#pragma unroll
        for (int bl = 0; bl < 2; ++bl) {
            char* P = bl ? PB : PA;
            const float* xp = X + (pt0 + bl * 16 + p) * 3;
            const float x0 = xp[0], x1 = xp[1], x2 = xp[2];
#pragma unroll
            for (int i = 0; i < 2; ++i) {
                const int jq = jq0 + 32 * i;     // 0..63
                const int j0 = jq * 4;
                const f32x4 w0 = *(const f32x4*)(W_in + j0);
                const f32x4 w1 = *(const f32x4*)(W_in + HIDDEN + j0);
                const f32x4 w2 = *(const f32x4*)(W_in + 2 * HIDDEN + j0);
                const f32x4 bq = *(const f32x4*)(b_in + j0);
                float o[NSTATE][4];
#pragma unroll
                for (int r = 0; r < 4; ++r) {
                    float z  = fmaf(x0, w0[r], fmaf(x1, w1[r], fmaf(x2, w2[r], bq[r])));
                    float a  = fast_tanh(z);
                    float td = 1.f - a * a;
                    float t2 = 2.f * a * td;
                    float sw = fmaf(w0[r], w0[r], w1[r] * w1[r]);
                    o[0][r] = a;
                    o[1][r] = td * w0[r];
                    o[2][r] = td * w1[r];
                    o[3][r] = fmaf(td, w2[r], t2 * sw);   // c0
                }
                const int kt = j0 >> 5, kg = (j0 >> 3) & 3, e0 = j0 & 7;
                const int sub = (kg * 16 + p) * 16 + e0 * 2;
#pragma unroll
                for (int s = 0; s < NSTATE; ++s) {
                    uint2 wv = { pack2(o[s][0], o[s][1]), pack2(o[s][2], o[s][3]) };
                    *(uint2*)(P + (s * 8 + kt) * 1024 + sub) = wv;
                }
            }
        }
    }
    __syncthreads();

    f32x4 accA[2][NSTATE], accB[2][NSTATE];

    // ---- prologue: accA = GEMM_A(layer 0) ----
    {
        const unsigned short* wb = whi + (0 * 16 + swid * 2) * 4096 + lane * 8;
        ACC_ZERO(accA);
        GEMM_QTR(accA, PA, wb, 0);
        GEMM_QTR(accA, PA, wb, 4);
    }
    __syncthreads();   // A reads done before tanh_A writes A

    // ---- pipelined hidden layers ----
#pragma unroll 1
    for (int l = 0; l < NLAYERS; ++l) {
        const int sLo = (l < NLAYERS - 1) ? 0 : 3;
        const f32x4 bs0 = *(const f32x4*)(b_h + l * HIDDEN + (swid * 2 + 0) * 16 + q * 4);
        const f32x4 bs1 = *(const f32x4*)(b_h + l * HIDDEN + (swid * 2 + 1) * 16 + q * 4);

        // phase X: GEMM_B(l) || tanh_A(l)
        {
            const unsigned short* wb = whi + (l * 16 + swid * 2) * 4096 + lane * 8;
            ACC_ZERO(accB);
            GEMM_QTR(accB, PB, wb, 0);
            TANH_UNIT(accA, PA, 0, bs0, sLo);
            GEMM_QTR(accB, PB, wb, 4);
            TANH_UNIT(accA, PA, 1, bs1, sLo);
        }
        __syncthreads();   // A writes + B reads complete

        // phase Y: GEMM_A(l+1) || tanh_B(l)   (last layer: tanh_B only)
        if (l < NLAYERS - 1) {
            const unsigned short* wb = whi + ((l + 1) * 16 + swid * 2) * 4096 + lane * 8;
            ACC_ZERO(accA);
            GEMM_QTR(accA, PA, wb, 0);
            TANH_UNIT(accB, PB, 0, bs0, sLo);
            GEMM_QTR(accA, PA, wb, 4);
            TANH_UNIT(accB, PB, 1, bs1, sLo);
        } else {
            TANH_UNIT(accB, PB, 0, bs0, sLo);
            TANH_UNIT(accB, PB, 1, bs1, sLo);
        }
        __syncthreads();   // B writes + A reads complete
    }

    // ---- output: residual = sum_j W_out[j] * c for both blocks ----
    {
        const int p   = tid & 15;
        const int jq0 = tid >> 4;          // 0..31
        float sumA = 0.f, sumB = 0.f;
#pragma unroll
        for (int i = 0; i < 2; ++i) {
            const int jq = jq0 + 32 * i, j0 = jq * 4;
            const int kt = j0 >> 5, kg = (j0 >> 3) & 3, e0 = j0 & 7;
            const int sub = (kg * 16 + p) * 16 + e0 * 2;
            uint2 cA = *(uint2*)(PA + (3 * 8 + kt) * 1024 + sub);
            uint2 cB = *(uint2*)(PB + (3 * 8 + kt) * 1024 + sub);
            f32x4 wo = *(const f32x4*)(W_out + j0);
            sumA = fmaf(wo[0], bf2f((unsigned short)(cA.x & 0xFFFF)), sumA);
            sumA = fmaf(wo[1], bf2f((unsigned short)(cA.x >> 16)),    sumA);
            sumA = fmaf(wo[2], bf2f((unsigned short)(cA.y & 0xFFFF)), sumA);
            sumA = fmaf(wo[3], bf2f((unsigned short)(cA.y >> 16)),    sumA);
            sumB = fmaf(wo[0], bf2f((unsigned short)(cB.x & 0xFFFF)), sumB);
            sumB = fmaf(wo[1], bf2f((unsigned short)(cB.x >> 16)),    sumB);
            sumB = fmaf(wo[2], bf2f((unsigned short)(cB.y & 0xFFFF)), sumB);
            sumB = fmaf(wo[3], bf2f((unsigned short)(cB.y >> 16)),    sumB);
        }
        red[jq0 * 16 + p]       = sumA;    // red aliases s=0 region: disjoint from s=3
        red[512 + jq0 * 16 + p] = sumB;
    }
    __syncthreads();
    if (tid < PPW) {                       // tid<16: block A points; 16..31: block B
        const int base = (tid >> 4) * 512, p = tid & 15;
        float s = 0.f;
        for (int g = 0; g < 32; ++g) s += red[base + g * 16 + p];   // fixed order
        double d = (double)s;
        sq[tid] = d * d;
    }
    __syncthreads();
    if (tid == 0) {
        double tot = 0.0;
        for (int p = 0; p < PPW; ++p) tot += sq[p];                 // fixed order
        partials[wg] = tot;
    }
}

__global__ void pinn_reduce_kernel(const double* __restrict__ partials, float* __restrict__ out)
{
    __shared__ double sh[256];
    double t = 0.0;
    for (int i = 0; i < NWG / 256; ++i) t += partials[threadIdx.x * (NWG / 256) + i]; // fixed order
    sh[threadIdx.x] = t;
    __syncthreads();
    for (int ofs = 128; ofs > 0; ofs >>= 1) {
        if ((int)threadIdx.x < ofs) sh[threadIdx.x] += sh[threadIdx.x + ofs];
        __syncthreads();
    }
    if (threadIdx.x == 0) {
        out[0] = (float)(sh[0] / (double)NPTS);  // pde_loss
        out[1] = 0.f;                            // ode_loss
    }
}

extern "C" void kernel_launch(void* const* d_in, const int* in_sizes, int n_in,
                              void* d_out, int out_size, void* d_ws, size_t ws_size,
                              hipStream_t stream)
{
    const float* X     = (const float*)d_in[0];
    const float* W_in  = (const float*)d_in[1];
    const float* b_in  = (const float*)d_in[2];
    const float* W_h   = (const float*)d_in[3];
    const float* b_h   = (const float*)d_in[4];
    const float* W_out = (const float*)d_in[5];
    // d_in[6] = b_out: constant output offset, zero derivative -> unused

    double*         partials = (double*)((char*)d_ws + WS_PARTIALS);
    unsigned short* whi      = (unsigned short*)((char*)d_ws + WS_WHI);
    float*          out      = (float*)d_out;

    const size_t lds_bytes = 2 * PLANE;  // 65536 B
    (void)hipFuncSetAttribute((const void*)pinn_mfma,
                              hipFuncAttributeMaxDynamicSharedMemorySize, (int)lds_bytes);

    hipLaunchKernelGGL(prep_w, dim3(512), dim3(64), 0, stream, W_h, whi);
    hipLaunchKernelGGL(pinn_mfma, dim3(NWG), dim3(512), lds_bytes, stream,
                       X, W_in, b_in, b_h, W_out, whi, partials);
    hipLaunchKernelGGL(pinn_reduce_kernel, dim3(1), dim3(256), 0, stream,
                       partials, out);
}

// Round 19
// 316.321 us; speedup vs baseline: 1.1704x; 1.1704x over previous
//
#include <hip/hip_runtime.h>
#include <hip/hip_bf16.h>

typedef __attribute__((ext_vector_type(8)))  short short8;
typedef __attribute__((ext_vector_type(4)))  float f32x4;
typedef __attribute__((ext_vector_type(16))) float f32x16;

#define HIDDEN   256
#define NLAYERS  4
#define NPTS     131072
#define PPW      32
#define NWG      (NPTS / PPW)          // 4096
#define NSTATE   4                     // h, g0, g1, c = gt - (s0+s1)
#define PLANE    65536                 // bytes: 4 states x 16 k-tiles x 1KB

// workspace layout (bytes)
#define WS_PARTIALS   0                          // 4096 doubles = 32 KB
#define WS_WHI        65536                      // 512 KB bf16 W fragments

__device__ __forceinline__ unsigned short f2bf(float f) {
    return __builtin_bit_cast(unsigned short, __float2bfloat16(f));   // HW RNE convert
}
__device__ __forceinline__ float bf2f(unsigned short h) {
    return __uint_as_float(((unsigned)h) << 16);
}
// pack two f32 -> one u32 of 2x bf16 (RNE); __hip_bfloat162 isn't trivially copyable
__device__ __forceinline__ unsigned pack2(float a, float b) {
    __hip_bfloat162 h2 = __float22bfloat162_rn(make_float2(a, b));
    unsigned u;
    __builtin_memcpy(&u, &h2, sizeof(u));
    return u;
}
__device__ __forceinline__ float fast_tanh(float z) {
    // tanh(z) = 1 - 2/(exp(2z)+1): exact at both saturations, no NaN
    float e = __expf(2.f * z);
    return 1.f - __fdividef(2.f, e + 1.f);
}

// ---------------- weight prep: W_h -> bf16, 32x32x16-A fragments ----------------
// Fragment (layer, jt, kt): lane l holds W[k][j] for j = jt*32 + (l&31),
// k = kt*16 + (l>>5)*8 + e (e=0..7). 1 KB per fragment.
__global__ void prep_w(const float* __restrict__ Wh, unsigned short* __restrict__ whi)
{
    int b    = blockIdx.x;               // 512 = 4 layers x 8 jt x 16 kt
    int lay  = b >> 7;
    int jt   = (b >> 4) & 7;
    int kt   = b & 15;
    int lane = threadIdx.x;              // 64
    int j    = jt * 32 + (lane & 31);
    int k0   = kt * 16 + (lane >> 5) * 8;
    const float* W = Wh + lay * 65536;
    int base = ((lay * 8 + jt) * 16 + kt) * 512 + lane * 8;  // ushort units
#pragma unroll
    for (int e = 0; e < 8; ++e)
        whi[base + e] = f2bf(W[(k0 + e) * HIDDEN + j]);
}

// ---------------- fused PINN kernel: 512 thr (8 waves), 64 KB LDS, 2 WGs/CU ----------------
// Single in-place bf16 state plane, 32x32x16 MFMA, 4 jet channels:
//   tile (s, kt) at byte (s*16+kt)*1024 (kt = k>>4, 16 tiles/state).
//   element (s, point p, k): byte = (s*16+(k>>4))*1024 + (((k>>3)&1)*32 + p)*16 + (k&7)*2
//   B-operand: lane l -> col(point) = l&31, k = kt*16 + (l>>5)*8 + e.
// Wave wid owns j-tile jt = wid (32 j rows). mfma(W_frag, S_frag) -> D: col = point,
//   row j = jt*32 + 8*(reg>>2) + 4*(lane>>5) + (reg&3)  -> 4 consecutive j per reg-quad.
// c-channel algebra: c = gt - S; GEMM linear => z_c = GEMM(c);
//   c' = td*z_c + 2*a*td*(z_g0^2 + z_g1^2)   (since -m2 = 2*a*td)
// Two barriers per layer (in-place plane: read -> WAR -> write).
__global__ __launch_bounds__(512, 4)
void pinn_mfma(const float* __restrict__ X,
               const float* __restrict__ W_in, const float* __restrict__ b_in,
               const float* __restrict__ b_h,  const float* __restrict__ W_out,
               const unsigned short* __restrict__ whi,
               double* __restrict__ partials)
{
    extern __shared__ char lds[];
    float*  red = (float*)lds;                // aliases s=0 tiles 0..1 (dead in output phase)
    double* sq  = (double*)(lds + 2048);      // aliases s=0 tile 2: 32 doubles

    const int tid  = threadIdx.x;
    const int lane = tid & 63;
    const int swid = __builtin_amdgcn_readfirstlane(tid >> 6);   // wave id = j-tile, SGPR
    const int h    = lane >> 5;          // k-half / row-half selector
    const int wg   = blockIdx.x;
    const int pt0  = wg * PPW;

    // ---- input layer: thread (p = tid&31, jseg = tid>>5) covers 16 j (4 quads) ----
    {
        const int p    = tid & 31;
        const int jseg = tid >> 5;               // 0..15
        const float* xp = X + (pt0 + p) * 3;
        const float x0 = xp[0], x1 = xp[1], x2 = xp[2];
#pragma unroll
        for (int qq = 0; qq < 4; ++qq) {
            const int j0 = jseg * 16 + qq * 4;
            const f32x4 w0 = *(const f32x4*)(W_in + j0);
            const f32x4 w1 = *(const f32x4*)(W_in + HIDDEN + j0);
            const f32x4 w2 = *(const f32x4*)(W_in + 2 * HIDDEN + j0);
            const f32x4 bq = *(const f32x4*)(b_in + j0);
            float o[NSTATE][4];
#pragma unroll
            for (int r = 0; r < 4; ++r) {
                float z  = fmaf(x0, w0[r], fmaf(x1, w1[r], fmaf(x2, w2[r], bq[r])));
                float a  = fast_tanh(z);
                float td = 1.f - a * a;
                float t2 = 2.f * a * td;         // = -m2
                float sw = fmaf(w0[r], w0[r], w1[r] * w1[r]);
                o[0][r] = a;
                o[1][r] = td * w0[r];
                o[2][r] = td * w1[r];
                o[3][r] = fmaf(td, w2[r], t2 * sw);   // c0 = gt0 - S0
            }
            const int sub = (((j0 >> 3) & 1) * 32 + p) * 16 + (j0 & 7) * 2;
#pragma unroll
            for (int s = 0; s < NSTATE; ++s) {
                uint2 wv = { pack2(o[s][0], o[s][1]), pack2(o[s][2], o[s][3]) };
                *(uint2*)(lds + (s * 16 + (j0 >> 4)) * 1024 + sub) = wv;
            }
        }
    }
    __syncthreads();

    // ---- hidden layers: single-product 32x32x16 MFMA, bf16 W and states, in-place ----
#pragma unroll 1
    for (int l = 0; l < NLAYERS; ++l) {
        const unsigned short* wbh = whi + ((l * 8 + swid) * 16) * 512 + lane * 8;
        const char* sbase = lds + lane * 16;

        f32x16 acc[NSTATE];
#pragma unroll
        for (int s = 0; s < NSTATE; ++s)
            acc[s] = (f32x16){0.f,0.f,0.f,0.f,0.f,0.f,0.f,0.f,0.f,0.f,0.f,0.f,0.f,0.f,0.f,0.f};

#pragma unroll 2
        for (int kt = 0; kt < 16; ++kt) {
            short8 wh = *(const short8*)(wbh + kt * 512);
            short8 sh_[NSTATE];
#pragma unroll
            for (int s = 0; s < NSTATE; ++s)
                sh_[s] = *(const short8*)(sbase + (s * 16 + kt) * 1024);

            __builtin_amdgcn_s_setprio(1);
#pragma unroll
            for (int s = 0; s < NSTATE; ++s)
                acc[s] = __builtin_amdgcn_mfma_f32_32x32x16_bf16(wh, sh_[s], acc[s], 0, 0, 0);
            __builtin_amdgcn_s_setprio(0);
        }

        __syncthreads();   // all GEMM reads done before in-place overwrite

        // tanh jet chain; reg-quad rq -> 4 consecutive j; packed b64 writes
#pragma unroll
        for (int rq = 0; rq < 4; ++rq) {
            const int j0 = swid * 32 + 8 * rq + 4 * h;
            const f32x4 bq = *(const f32x4*)(b_h + l * HIDDEN + j0);
            float o[NSTATE][4];
#pragma unroll
            for (int rr = 0; rr < 4; ++rr) {
                const int r = rq * 4 + rr;
                float z0 = acc[0][r] + bq[rr];
                float z1 = acc[1][r], z2 = acc[2][r], zc = acc[3][r];
                float a  = fast_tanh(z0);
                float td = 1.f - a * a;
                float t2 = 2.f * a * td;         // = -m2
                o[0][rr] = a;
                o[1][rr] = td * z1;
                o[2][rr] = td * z2;
                o[3][rr] = fmaf(td, zc, t2 * fmaf(z1, z1, z2 * z2));   // c'
            }
            const int sub = ((rq & 1) * 32 + (lane & 31)) * 16 + 8 * h;
            const int ktj = swid * 2 + (rq >> 1);
            const int sLo = (l < NLAYERS - 1) ? 0 : 3;   // last layer: only c live
#pragma unroll
            for (int s = 0; s < NSTATE; ++s) {
                if (s < sLo) continue;
                uint2 wv = { pack2(o[s][0], o[s][1]), pack2(o[s][2], o[s][3]) };
                *(uint2*)(lds + (s * 16 + ktj) * 1024 + sub) = wv;
            }
        }
        __syncthreads();   // writes visible before next layer's reads
    }

    // ---- output: residual_p = sum_j W_out[j] * c; reads s=3 tiles only ----
    {
        const int p    = tid & 31;
        const int jseg = tid >> 5;          // 0..15
        float sum = 0.f;
#pragma unroll
        for (int qq = 0; qq < 4; ++qq) {
            const int j0  = jseg * 16 + qq * 4;
            const int sub = (((j0 >> 3) & 1) * 32 + p) * 16 + (j0 & 7) * 2;
            uint2 cv = *(uint2*)(lds + (3 * 16 + (j0 >> 4)) * 1024 + sub);
            f32x4 wo = *(const f32x4*)(W_out + j0);
            sum = fmaf(wo[0], bf2f((unsigned short)(cv.x & 0xFFFF)), sum);
            sum = fmaf(wo[1], bf2f((unsigned short)(cv.x >> 16)),    sum);
            sum = fmaf(wo[2], bf2f((unsigned short)(cv.y & 0xFFFF)), sum);
            sum = fmaf(wo[3], bf2f((unsigned short)(cv.y >> 16)),    sum);
        }
        red[jseg * 32 + p] = sum;           // red aliases s=0 tiles: disjoint from s=3 reads
    }
    __syncthreads();
    if (tid < PPW) {
        float s = 0.f;
        for (int g = 0; g < 16; ++g) s += red[g * 32 + tid];   // fixed order
        double d = (double)s;
        sq[tid] = d * d;
    }
    __syncthreads();
    if (tid == 0) {
        double tot = 0.0;
        for (int p = 0; p < PPW; ++p) tot += sq[p];            // fixed order
        partials[wg] = tot;
    }
}

__global__ void pinn_reduce_kernel(const double* __restrict__ partials, float* __restrict__ out)
{
    __shared__ double sh[256];
    double t = 0.0;
    for (int i = 0; i < NWG / 256; ++i) t += partials[threadIdx.x * (NWG / 256) + i]; // fixed order
    sh[threadIdx.x] = t;
    __syncthreads();
    for (int ofs = 128; ofs > 0; ofs >>= 1) {
        if ((int)threadIdx.x < ofs) sh[threadIdx.x] += sh[threadIdx.x + ofs];
        __syncthreads();
    }
    if (threadIdx.x == 0) {
        out[0] = (float)(sh[0] / (double)NPTS);  // pde_loss
        out[1] = 0.f;                            // ode_loss
    }
}

extern "C" void kernel_launch(void* const* d_in, const int* in_sizes, int n_in,
                              void* d_out, int out_size, void* d_ws, size_t ws_size,
                              hipStream_t stream)
{
    const float* X     = (const float*)d_in[0];
    const float* W_in  = (const float*)d_in[1];
    const float* b_in  = (const float*)d_in[2];
    const float* W_h   = (const float*)d_in[3];
    const float* b_h   = (const float*)d_in[4];
    const float* W_out = (const float*)d_in[5];
    // d_in[6] = b_out: constant output offset, zero derivative -> unused

    double*         partials = (double*)((char*)d_ws + WS_PARTIALS);
    unsigned short* whi      = (unsigned short*)((char*)d_ws + WS_WHI);
    float*          out      = (float*)d_out;

    const size_t lds_bytes = PLANE;      // 65536 B -> 2 WGs/CU
    (void)hipFuncSetAttribute((const void*)pinn_mfma,
                              hipFuncAttributeMaxDynamicSharedMemorySize, (int)lds_bytes);

    hipLaunchKernelGGL(prep_w, dim3(512), dim3(64), 0, stream, W_h, whi);
    hipLaunchKernelGGL(pinn_mfma, dim3(NWG), dim3(512), lds_bytes, stream,
                       X, W_in, b_in, b_h, W_out, whi, partials);
    hipLaunchKernelGGL(pinn_reduce_kernel, dim3(1), dim3(256), 0, stream,
                       partials, out);
}